// Round 6
// baseline (86.883 us; speedup 1.0000x reference)
//
#include <hip/hip_runtime.h>
#include <hip/hip_bf16.h>
#include <hip/hip_fp8.h>

typedef __attribute__((ext_vector_type(4))) float f32x4;
typedef long long i64;

// exp(v/T - 5) with T=0.2  ==  exp2( (v-1) * 5*log2(e) )
#define EXP_SCALE 7.213475204444817f

__device__ __forceinline__ float fast_exp2(float x) {
#if __has_builtin(__builtin_amdgcn_exp2f)
  return __builtin_amdgcn_exp2f(x);
#else
  return exp2f(x);
#endif
}

// z is stored as fp8 e4m3, SWIZZLED in MFMA-fragment order (byte units):
//   byte addr = tile*2048 + kk*512 + slot*8 + rem
// tile = row>>4, c = row&15; element e: kk = e>>5, q = (e>>3)&3, rem = e&7,
// slot = q*16 + c. A wave (lane = q*16+c) loads one (tile,kk) fragment as
// one contiguous 512B load (8B/lane dwordx2).

// Kernel 1: L2-normalize rows -> swizzled fp8 z. Zeroes out[0].
__global__ __launch_bounds__(256) void k_normalize(
    const float* __restrict__ emb_i, const float* __restrict__ emb_j,
    unsigned char* __restrict__ z, float* __restrict__ out)
{
  if (blockIdx.x == 0 && threadIdx.x == 0) out[0] = 0.0f;
  const int t = threadIdx.x;
  const int c = t >> 4;               // row within tile (0..15)
  const int sub = t & 15;             // 8-element block within row
  const int row = (blockIdx.x << 4) + c;
  const float* src = (row < 4096) ? (emb_i + row * 128) : (emb_j + (row - 4096) * 128);
  float4 v0 = reinterpret_cast<const float4*>(src)[sub * 2];
  float4 v1 = reinterpret_cast<const float4*>(src)[sub * 2 + 1];
  float ss = v0.x*v0.x + v0.y*v0.y + v0.z*v0.z + v0.w*v0.w
           + v1.x*v1.x + v1.y*v1.y + v1.z*v1.z + v1.w*v1.w;
  #pragma unroll
  for (int m = 1; m < 16; m <<= 1) ss += __shfl_xor(ss, m, 64);
  float rinv = 1.0f / sqrtf(ss);
  unsigned char st[8];
  st[0] = __hip_fp8_e4m3(v0.x * rinv).__x;
  st[1] = __hip_fp8_e4m3(v0.y * rinv).__x;
  st[2] = __hip_fp8_e4m3(v0.z * rinv).__x;
  st[3] = __hip_fp8_e4m3(v0.w * rinv).__x;
  st[4] = __hip_fp8_e4m3(v1.x * rinv).__x;
  st[5] = __hip_fp8_e4m3(v1.y * rinv).__x;
  st[6] = __hip_fp8_e4m3(v1.z * rinv).__x;
  st[7] = __hip_fp8_e4m3(v1.w * rinv).__x;
  unsigned char* dst = z + blockIdx.x * 2048 + (sub >> 2) * 512 +
                       (((sub & 3) << 4) + c) * 8;
  *reinterpret_cast<i64*>(dst) = *reinterpret_cast<i64*>(st);
}

// Kernel 2 (symmetric, fp8 MFMA), atomic-free, 32-ROW CELLS:
// cell = 32 rows x 512 cols. For chunk ch (cols [512ch,512ch+512)),
// rb = 0..16(ch+1)-1, start(ch) = 8ch(ch+1) -> 2176 cells total.
// upper (strictly above diagonal band) iff rb < 16ch: also store transposed
// col-sums -> cpart[4096*ch*(ch-1) + rb*512 + localcol] (unique slot).
// Row-sums -> rpart[ch][R0+t] (unique slot). Diagonal exp term (==1) kept;
// k_finish subtracts 1.
// Pipeline: triple-buffered B, fully unrolled, per-block rotated walk
// (rot = bid&7) to de-convoy L2 bursts across blocks sharing a chunk.
__global__ __launch_bounds__(256, 4) void k_simlse(
    const unsigned char* __restrict__ z,
    float* __restrict__ rpart,    // [16][8192] row partial sums
    float* __restrict__ cpart,    // packed col partials, 983040 floats
    float* __restrict__ rowpos)   // [4096] (row r>=4096 mirrors r-4096)
{
  const int w = threadIdx.x >> 6;
  const int lane = threadIdx.x & 63;
  const int q = lane >> 4;
  const int c = lane & 15;
  const int bid = blockIdx.x;

  // closed-form ch from start(ch) = 8ch(ch+1): ch = (sqrt(1+bid/2)-1)/2,
  // integer fixups guard fp rounding.
  int ch = (int)((sqrtf(1.0f + 0.5f * (float)bid) - 1.0f) * 0.5f);
  if (bid >= 8 * (ch + 1) * (ch + 2)) ++ch;
  else if (bid < 8 * ch * (ch + 1)) --ch;
  const int rb = bid - 8 * ch * (ch + 1);          // 0 .. 16(ch+1)-1
  const int R0 = rb << 5;                          // 32-row block
  const bool upper = (rb < (ch << 4));             // strictly above diagonal band
  const int rot = bid & 7;

  // ---- A fragments straight from global: 8 contiguous 512B wave loads ----
  i64 a[2][4];
  {
    const unsigned char* ap = z + (R0 >> 4) * 2048 + (lane << 3);
    #pragma unroll
    for (int rg = 0; rg < 2; ++rg)
      #pragma unroll
      for (int kk = 0; kk < 4; ++kk)
        a[rg][kk] = *reinterpret_cast<const i64*>(ap + rg * 2048 + kk * 512);
  }

  float acc[2][4];
  #pragma unroll
  for (int rg = 0; rg < 2; ++rg)
    #pragma unroll
    for (int e = 0; e < 4; ++e) acc[rg][e] = 0.0f;
  float pacc[4] = {0.f, 0.f, 0.f, 0.f};
  float colp[8];
  #pragma unroll
  for (int i = 0; i < 8; ++i) colp[i] = 0.0f;

  __shared__ float lsum[4][32];
  __shared__ float lpos[4][16];

  // wave w walks 16-col tiles ct = 32ch + w + 4*idx, idx = rotated 0..7
  const int ct0 = (ch << 5) + w;
  const unsigned char* bwave = z + ct0 * 2048 + (lane << 3);

  // positive tiles: pos0t (even), pos0t+1; owned iff chunk matches.
  const int pos0t = ((R0 + 4096) & 8191) >> 4;
  const int ipb = ((pos0t >> 5) == ch) ? ((pos0t & 31) >> 2) : -99;
  const int pw = pos0t & 3;                        // 0 or 2: waves pw, pw+1

  i64 b0[4], b1[4], b2[4];
  auto ldb = [&](i64 (&dst)[4], int idx) {
    const unsigned char* p = bwave + idx * 8192;   // stride 4 tiles = 8KB
    dst[0] = *reinterpret_cast<const i64*>(p);
    dst[1] = *reinterpret_cast<const i64*>(p + 512);
    dst[2] = *reinterpret_cast<const i64*>(p + 1024);
    dst[3] = *reinterpret_cast<const i64*>(p + 1536);
  };

  auto process = [&](const i64 (&bb)[4], int idx, float& cpj) {
    f32x4 cc[2];
    #pragma unroll
    for (int rr = 0; rr < 2; ++rr) cc[rr] = f32x4{0.f, 0.f, 0.f, 0.f};
    #pragma unroll
    for (int kk = 0; kk < 4; ++kk)
      #pragma unroll
      for (int rr = 0; rr < 2; ++rr)
        cc[rr] = __builtin_amdgcn_mfma_f32_16x16x32_fp8_fp8(
            a[rr][kk], bb[kk], cc[rr], 0, 0, 0);
    float cp0 = 0.0f, cp1 = 0.0f;       // two chains to cut dep latency
    #pragma unroll
    for (int rr = 0; rr < 2; ++rr)
      #pragma unroll
      for (int e = 0; e < 4; ++e) {
        float tv = fast_exp2(__builtin_fmaf(cc[rr][e], EXP_SCALE, -EXP_SCALE));
        acc[rr][e] += tv;
        if (upper) { if (rr & 1) cp1 += tv; else cp0 += tv; }
      }
    if (upper) cpj = cp0 + cp1;
    if (idx == ipb) {                   // rare, wave-uniform
      #pragma unroll
      for (int rr = 0; rr < 2; ++rr) {
        if (w == pw + rr) {             // wave holding pos tile pos0t+rr
          #pragma unroll
          for (int e = 0; e < 4; ++e)
            if (c == ((q << 2) + e)) pacc[e] = cc[rr][e] * 5.0f;
        }
      }
    }
  };

  // Fully-unrolled triple-buffered pipeline over rotated tile order.
  #define IDX(j) (((j) + rot) & 7)
  ldb(b0, IDX(0)); ldb(b1, IDX(1));
  ldb(b2, IDX(2)); process(b0, IDX(0), colp[0]);
  ldb(b0, IDX(3)); process(b1, IDX(1), colp[1]);
  ldb(b1, IDX(4)); process(b2, IDX(2), colp[2]);
  ldb(b2, IDX(5)); process(b0, IDX(3), colp[3]);
  ldb(b0, IDX(6)); process(b1, IDX(4), colp[4]);
  ldb(b1, IDX(7)); process(b2, IDX(5), colp[5]);
  process(b0, IDX(6), colp[6]);
  process(b1, IDX(7), colp[7]);

  // Deferred colsum reduction -> PLAIN stores into this cell's private slice
  if (upper) {
    const int cbase = 4096 * ch * (ch - 1) + (rb << 9);
    #pragma unroll
    for (int j = 0; j < 8; ++j) {
      float v = colp[j];
      v += __shfl_xor(v, 16, 64);
      v += __shfl_xor(v, 32, 64);
      if (lane < 16)                    // local col = (w + 4*IDX(j))*16 + c
        cpart[cbase + ((w + (IDX(j) << 2)) << 4) + c] = v;
    }
  }

  // Reduce row-sums over the 16 cols per tile (c-group: xor 1,2,4,8)
  #pragma unroll
  for (int m = 1; m < 16; m <<= 1) {
    #pragma unroll
    for (int rg = 0; rg < 2; ++rg)
      #pragma unroll
      for (int e = 0; e < 4; ++e)
        acc[rg][e] += __shfl_xor(acc[rg][e], m, 64);
    #pragma unroll
    for (int e = 0; e < 4; ++e) pacc[e] += __shfl_xor(pacc[e], m, 64);
  }

  if (c == 0) {
    #pragma unroll
    for (int rg = 0; rg < 2; ++rg)
      #pragma unroll
      for (int e = 0; e < 4; ++e)
        lsum[w][rg * 16 + (q << 2) + e] = acc[rg][e];
    #pragma unroll
    for (int e = 0; e < 4; ++e) lpos[w][(q << 2) + e] = pacc[e];
  }
  __syncthreads();

  if (threadIdx.x < 32) {
    const int t = threadIdx.x;
    float s = lsum[0][t] + lsum[1][t] + lsum[2][t] + lsum[3][t];
    rpart[(ch << 13) + R0 + t] = s;     // plain store, unique (ch,row) slot
    if (ipb != -99)                     // this cell owns the positive cols
      rowpos[R0 + t] = lpos[pw + (t >> 4)][t & 15];
  }
}

// Kernel 3: gather partials. rowsum[r] = sum_{ch=r>>9}^{15} rpart[ch][r]
//   + sum_{rb=0}^{16*(r>>9)-1} cpart[4096*chr*(chr-1) + rb*512 + (r&511)].
// Every summed slot was written by an existing cell; no zero-init needed.
// tot = rowsum - 1 (diag); lse = 5 + log(tot); loss = mean(lse - pos).
__global__ __launch_bounds__(256) void k_finish(
    const float* __restrict__ rpart, const float* __restrict__ cpart,
    const float* __restrict__ rowpos, float* __restrict__ out)
{
  const int r = blockIdx.x * 256 + threadIdx.x;
  const int chr = r >> 9;

  float rs = 0.0f;
  #pragma unroll 4
  for (int ch = chr; ch < 16; ++ch) rs += rpart[(ch << 13) + r];

  const int nrb = chr << 4;                        // multiple of 16
  const float* cb = cpart + 4096 * chr * (chr - 1) + (r & 511);
  float cs0 = 0.f, cs1 = 0.f, cs2 = 0.f, cs3 = 0.f;
  #pragma unroll 2
  for (int rb = 0; rb < nrb; rb += 4) {
    cs0 += cb[(rb + 0) << 9];
    cs1 += cb[(rb + 1) << 9];
    cs2 += cb[(rb + 2) << 9];
    cs3 += cb[(rb + 3) << 9];
  }

  float tot = rs + ((cs0 + cs1) + (cs2 + cs3)) - 1.0f;
  float v = 5.0f + logf(tot) - rowpos[r & 4095];
  #pragma unroll
  for (int m = 1; m < 64; m <<= 1) v += __shfl_xor(v, m, 64);
  __shared__ float red[4];
  if ((threadIdx.x & 63) == 0) red[threadIdx.x >> 6] = v;
  __syncthreads();
  if (threadIdx.x == 0)
    atomicAdd(out, (red[0] + red[1] + red[2] + red[3]) * (1.0f / 8192.0f));
}

extern "C" void kernel_launch(void* const* d_in, const int* in_sizes, int n_in,
                              void* d_out, int out_size, void* d_ws, size_t ws_size,
                              hipStream_t stream) {
  const float* emb_i = (const float*)d_in[0];
  const float* emb_j = (const float*)d_in[1];
  unsigned char* z = (unsigned char*)d_ws;                   // 1 MB fp8, swizzled
  float* rpart = (float*)((char*)d_ws + (1 << 20));          // 16*8192*4 = 512 KB
  float* cpart = (float*)((char*)d_ws + 1572864);            // 983040 floats = 3.75 MB
  float* rowpos = (float*)((char*)d_ws + 5505024);           // [4096] = 16 KB
  float* out = (float*)d_out;

  k_normalize<<<512, 256, 0, stream>>>(emb_i, emb_j, z, out);
  k_simlse<<<2176, 256, 0, stream>>>(z, rpart, cpart, rowpos);
  k_finish<<<32, 256, 0, stream>>>(rpart, cpart, rowpos, out);
}

// Round 7
// 81.825 us; speedup vs baseline: 1.0618x; 1.0618x over previous
//
#include <hip/hip_runtime.h>
#include <hip/hip_bf16.h>
#include <hip/hip_fp8.h>

typedef __attribute__((ext_vector_type(4))) float f32x4;
typedef long long i64;

// exp(v/T - 5) with T=0.2  ==  exp2( (v-1) * 5*log2(e) )
#define EXP_SCALE 7.213475204444817f

__device__ __forceinline__ float fast_exp2(float x) {
#if __has_builtin(__builtin_amdgcn_exp2f)
  return __builtin_amdgcn_exp2f(x);
#else
  return exp2f(x);
#endif
}

// z is stored as fp8 e4m3, SWIZZLED in MFMA-fragment order (byte units):
//   byte addr = tile*2048 + kk*512 + slot*8 + rem
// tile = row>>4, c = row&15; element e: kk = e>>5, q = (e>>3)&3, rem = e&7,
// slot = q*16 + c. A wave (lane = q*16+c) loads one (tile,kk) fragment as
// one contiguous 512B load (8B/lane dwordx2).

// Kernel 1: L2-normalize rows -> swizzled fp8 z. Zeroes out[0].
__global__ __launch_bounds__(256) void k_normalize(
    const float* __restrict__ emb_i, const float* __restrict__ emb_j,
    unsigned char* __restrict__ z, float* __restrict__ out)
{
  if (blockIdx.x == 0 && threadIdx.x == 0) out[0] = 0.0f;
  const int t = threadIdx.x;
  const int c = t >> 4;               // row within tile (0..15)
  const int sub = t & 15;             // 8-element block within row
  const int row = (blockIdx.x << 4) + c;
  const float* src = (row < 4096) ? (emb_i + row * 128) : (emb_j + (row - 4096) * 128);
  float4 v0 = reinterpret_cast<const float4*>(src)[sub * 2];
  float4 v1 = reinterpret_cast<const float4*>(src)[sub * 2 + 1];
  float ss = v0.x*v0.x + v0.y*v0.y + v0.z*v0.z + v0.w*v0.w
           + v1.x*v1.x + v1.y*v1.y + v1.z*v1.z + v1.w*v1.w;
  #pragma unroll
  for (int m = 1; m < 16; m <<= 1) ss += __shfl_xor(ss, m, 64);
  float rinv = 1.0f / sqrtf(ss);
  unsigned char st[8];
  st[0] = __hip_fp8_e4m3(v0.x * rinv).__x;
  st[1] = __hip_fp8_e4m3(v0.y * rinv).__x;
  st[2] = __hip_fp8_e4m3(v0.z * rinv).__x;
  st[3] = __hip_fp8_e4m3(v0.w * rinv).__x;
  st[4] = __hip_fp8_e4m3(v1.x * rinv).__x;
  st[5] = __hip_fp8_e4m3(v1.y * rinv).__x;
  st[6] = __hip_fp8_e4m3(v1.z * rinv).__x;
  st[7] = __hip_fp8_e4m3(v1.w * rinv).__x;
  unsigned char* dst = z + blockIdx.x * 2048 + (sub >> 2) * 512 +
                       (((sub & 3) << 4) + c) * 8;
  *reinterpret_cast<i64*>(dst) = *reinterpret_cast<i64*>(st);
}

// Kernel 2 (symmetric, fp8 MFMA), atomic-free, 128-ROW x 512-COL CELLS,
// 8-wave (512-thread) blocks = 2 row-groups x 4 col-walks.
// For chunk ch (cols [512ch, 512ch+512)): rb = 0..4(ch+1)-1,
// start(ch) = 2ch(ch+1) -> 544 cells (53% of full work). Halves total
// B-panel traffic vs 64-row cells (round-6 A/B: traffic scales wall time).
// upper iff rb < 4ch: transposed col-sums -> cpart (unique slot per
// (ch,rb,rowgroup,col)). Row-sums -> rpart[ch][row] (unique slot).
// Diagonal exp term (==1 for unit rows) kept; k_finish subtracts 1.
// Per-wave math is the round-5-verified body with R0 -> R0 + 64*g.
__global__ __launch_bounds__(512, 4) void k_simlse(
    const unsigned char* __restrict__ z,
    float* __restrict__ rpart,    // [16][8192] row partial sums
    float* __restrict__ cpart,    // packed col partials, 491520 floats
    float* __restrict__ rowpos)   // [4096] (row r>=4096 mirrors r-4096)
{
  const int w = threadIdx.x >> 6;
  const int g = w >> 2;               // row-group (0..1): rows R0+64g..+64
  const int cw = w & 3;               // column-walk wave (0..3)
  const int lane = threadIdx.x & 63;
  const int q = lane >> 4;
  const int c = lane & 15;
  const int bid = blockIdx.x;

  // closed-form ch from start(ch) = 2ch(ch+1); integer fixups guard rounding.
  int ch = (int)((sqrtf((float)(1 + 2 * bid)) - 1.0f) * 0.5f);
  if (bid >= 2 * (ch + 1) * (ch + 2)) ++ch;
  else if (bid < 2 * ch * (ch + 1)) --ch;
  const int rb = bid - 2 * ch * (ch + 1);          // 0 .. 4(ch+1)-1
  const int R0 = rb << 7;                          // 128-row block
  const bool upper = (rb < (ch << 2));             // strictly above diagonal band

  // ---- A fragments (this wave's 64-row group): 16 contiguous 512B loads ----
  i64 a[4][4];
  {
    const unsigned char* ap = z + ((R0 >> 4) + (g << 2)) * 2048 + (lane << 3);
    #pragma unroll
    for (int rg = 0; rg < 4; ++rg)
      #pragma unroll
      for (int kk = 0; kk < 4; ++kk)
        a[rg][kk] = *reinterpret_cast<const i64*>(ap + rg * 2048 + kk * 512);
  }

  float acc[4][4];
  #pragma unroll
  for (int rg = 0; rg < 4; ++rg)
    #pragma unroll
    for (int e = 0; e < 4; ++e) acc[rg][e] = 0.0f;
  float pacc[4] = {0.f, 0.f, 0.f, 0.f};
  float colp[8];
  #pragma unroll
  for (int i = 0; i < 8; ++i) colp[i] = 0.0f;

  __shared__ float lsum[8][64];
  __shared__ float lpos[8][16];

  // wave (g,cw) walks 16-col tiles ct = 32ch + cw + 4i, i = 0..7
  const int ct0 = (ch << 5) + cw;
  const unsigned char* bwave = z + ct0 * 2048 + (lane << 3);

  // positive tiles for this wave's row-group: pos0t..pos0t+3 (pos0t 4-aligned;
  // both row-groups land in the same 32-tile chunk since pos0t is 8-aligned
  // at g=0). Owned iff the chunk matches this cell's ch.
  const int pos0t = ((R0 + (g << 6) + 4096) & 8191) >> 4;
  const int ipb = ((pos0t >> 5) == ch) ? ((pos0t & 31) >> 2) : -99;

  i64 b0[4], b1[4];
  auto ldb = [&](i64 (&dst)[4], int idx) {
    const unsigned char* p = bwave + idx * 8192;   // stride 4 tiles = 8KB
    dst[0] = *reinterpret_cast<const i64*>(p);
    dst[1] = *reinterpret_cast<const i64*>(p + 512);
    dst[2] = *reinterpret_cast<const i64*>(p + 1024);
    dst[3] = *reinterpret_cast<const i64*>(p + 1536);
  };

  auto process = [&](const i64 (&bb)[4], int i) {
    f32x4 cc[4];
    #pragma unroll
    for (int rr = 0; rr < 4; ++rr) cc[rr] = f32x4{0.f, 0.f, 0.f, 0.f};
    #pragma unroll
    for (int kk = 0; kk < 4; ++kk)
      #pragma unroll
      for (int rr = 0; rr < 4; ++rr)
        cc[rr] = __builtin_amdgcn_mfma_f32_16x16x32_fp8_fp8(
            a[rr][kk], bb[kk], cc[rr], 0, 0, 0);
    float cp0 = 0.0f, cp1 = 0.0f;       // two chains to cut dep latency
    #pragma unroll
    for (int rr = 0; rr < 4; ++rr)
      #pragma unroll
      for (int e = 0; e < 4; ++e) {
        float tv = fast_exp2(__builtin_fmaf(cc[rr][e], EXP_SCALE, -EXP_SCALE));
        acc[rr][e] += tv;
        if (upper) { if (rr & 1) cp1 += tv; else cp0 += tv; }
      }
    if (upper) colp[i] = cp0 + cp1;     // shfl deferred out of the loop
    if (i == ipb) {                     // rare, wave-uniform
      // wave (g,cw) holds tile pos0t+cw; only A-subtile rr==cw has its
      // positive diagonal in this tile.
      #pragma unroll
      for (int rr = 0; rr < 4; ++rr) {
        if (rr == cw) {
          #pragma unroll
          for (int e = 0; e < 4; ++e)
            if (c == ((q << 2) + e)) pacc[e] = cc[rr][e] * 5.0f;
        }
      }
    }
  };

  ldb(b0, 0);
  #pragma unroll 1
  for (int i = 0; i < 8; i += 2) {
    ldb(b1, i + 1);
    process(b0, i);
    if (i + 2 < 8) ldb(b0, i + 2);
    process(b1, i + 1);
  }

  // Deferred colsum reduction -> PLAIN stores into this cell's private slice
  if (upper) {
    const int cbase = 2048 * ch * (ch - 1) + (rb << 10) + (g << 9);
    #pragma unroll
    for (int j = 0; j < 8; ++j) {
      float v = colp[j];
      v += __shfl_xor(v, 16, 64);
      v += __shfl_xor(v, 32, 64);
      if (lane < 16)                    // local col = (cw + 4j)*16 + c
        cpart[cbase + ((cw + (j << 2)) << 4) + c] = v;
    }
  }

  // Reduce row-sums over the 16 cols per tile (c-group: xor 1,2,4,8)
  #pragma unroll
  for (int m = 1; m < 16; m <<= 1) {
    #pragma unroll
    for (int rg = 0; rg < 4; ++rg)
      #pragma unroll
      for (int e = 0; e < 4; ++e)
        acc[rg][e] += __shfl_xor(acc[rg][e], m, 64);
    #pragma unroll
    for (int e = 0; e < 4; ++e) pacc[e] += __shfl_xor(pacc[e], m, 64);
  }

  if (c == 0) {
    #pragma unroll
    for (int rg = 0; rg < 4; ++rg)
      #pragma unroll
      for (int e = 0; e < 4; ++e)
        lsum[w][rg * 16 + (q << 2) + e] = acc[rg][e];
    #pragma unroll
    for (int e = 0; e < 4; ++e) lpos[w][(q << 2) + e] = pacc[e];
  }
  __syncthreads();

  if (threadIdx.x < 128) {
    const int t = threadIdx.x;            // row R0 + t
    const int gg = t >> 6, tr = t & 63;
    float s = lsum[(gg << 2) + 0][tr] + lsum[(gg << 2) + 1][tr]
            + lsum[(gg << 2) + 2][tr] + lsum[(gg << 2) + 3][tr];
    rpart[(ch << 13) + R0 + t] = s;       // plain store, unique (ch,row) slot
    // chunk-match is identical for both row-groups; recompute from scalars
    const bool haspos = (((((R0 + 4096) & 8191) >> 4) >> 5) == ch);
    if (haspos)                           // only cells with R0 < 4096 qualify
      rowpos[R0 + t] = lpos[(gg << 2) + (tr >> 4)][t & 15];
  }
}

// Kernel 3: gather partials. rowsum[r] = sum_{ch=r>>9}^{15} rpart[ch][r]
//   + sum_{k=0}^{8*(r>>9)-1} cpart[2048*chr*(chr-1) + k*512 + (r&511)]
// (k enumerates (rb,g) pairs; every summed slot written by an existing cell;
// no zero-init needed). tot = rowsum - 1; lse = 5 + log(tot);
// loss = mean(lse - pos).
__global__ __launch_bounds__(256) void k_finish(
    const float* __restrict__ rpart, const float* __restrict__ cpart,
    const float* __restrict__ rowpos, float* __restrict__ out)
{
  const int r = blockIdx.x * 256 + threadIdx.x;
  const int chr = r >> 9;

  float rs = 0.0f;
  #pragma unroll 4
  for (int ch = chr; ch < 16; ++ch) rs += rpart[(ch << 13) + r];

  const int nv = chr << 3;                         // multiple of 8
  const float* cb = cpart + 2048 * chr * (chr - 1) + (r & 511);
  float cs0 = 0.f, cs1 = 0.f, cs2 = 0.f, cs3 = 0.f;
  #pragma unroll 2
  for (int k = 0; k < nv; k += 4) {
    cs0 += cb[(k + 0) << 9];
    cs1 += cb[(k + 1) << 9];
    cs2 += cb[(k + 2) << 9];
    cs3 += cb[(k + 3) << 9];
  }

  float tot = rs + ((cs0 + cs1) + (cs2 + cs3)) - 1.0f;
  float v = 5.0f + logf(tot) - rowpos[r & 4095];
  #pragma unroll
  for (int m = 1; m < 64; m <<= 1) v += __shfl_xor(v, m, 64);
  __shared__ float red[4];
  if ((threadIdx.x & 63) == 0) red[threadIdx.x >> 6] = v;
  __syncthreads();
  if (threadIdx.x == 0)
    atomicAdd(out, (red[0] + red[1] + red[2] + red[3]) * (1.0f / 8192.0f));
}

extern "C" void kernel_launch(void* const* d_in, const int* in_sizes, int n_in,
                              void* d_out, int out_size, void* d_ws, size_t ws_size,
                              hipStream_t stream) {
  const float* emb_i = (const float*)d_in[0];
  const float* emb_j = (const float*)d_in[1];
  unsigned char* z = (unsigned char*)d_ws;                   // 1 MB fp8, swizzled
  float* rpart = (float*)((char*)d_ws + (1 << 20));          // 16*8192*4 = 512 KB
  float* cpart = (float*)((char*)d_ws + 1572864);            // 491520 floats = 1.875 MB
  float* rowpos = (float*)((char*)d_ws + 3538944);           // [4096] = 16 KB
  float* out = (float*)d_out;

  k_normalize<<<512, 256, 0, stream>>>(emb_i, emb_j, z, out);
  k_simlse<<<544, 512, 0, stream>>>(z, rpart, cpart, rowpos);
  k_finish<<<32, 256, 0, stream>>>(rpart, cpart, rowpos, out);
}